// Round 1
// baseline (878.432 us; speedup 1.0000x reference)
//
#include <hip/hip_runtime.h>
#include <hip/hip_bf16.h>

#define NN 100000
#define NE 1600000
#define NG 5000
#define FIN 11
#define HID 128
#define NC 19

// ---------- graph preprocessing ----------

__global__ __launch_bounds__(256) void k_degree(const int* __restrict__ ei, int* __restrict__ deg) {
    int e = blockIdx.x * 256 + threadIdx.x;
    if (e < NE) atomicAdd(&deg[ei[NE + e]], 1);
}

__global__ __launch_bounds__(256) void k_dis(const int* __restrict__ deg, float* __restrict__ dis) {
    int v = blockIdx.x * 256 + threadIdx.x;
    if (v < NN) dis[v] = rsqrtf((float)deg[v] + 1.0f);
}

__global__ __launch_bounds__(256) void k_scan1(const int* __restrict__ deg, int* __restrict__ rp, int* __restrict__ bsum) {
    __shared__ int s[256];
    int t = threadIdx.x;
    int i = blockIdx.x * 256 + t;
    int v = (i < NN) ? deg[i] : 0;
    s[t] = v;
    __syncthreads();
    for (int off = 1; off < 256; off <<= 1) {
        int add = (t >= off) ? s[t - off] : 0;
        __syncthreads();
        s[t] += add;
        __syncthreads();
    }
    if (i < NN) rp[i] = s[t] - v;            // exclusive within block
    if (t == 255) bsum[blockIdx.x] = s[255]; // block total
}

__global__ __launch_bounds__(512) void k_scan2(int* __restrict__ bsum, int nb) {
    __shared__ int s[512];
    int t = threadIdx.x;
    int v = (t < nb) ? bsum[t] : 0;
    s[t] = v;
    __syncthreads();
    for (int off = 1; off < 512; off <<= 1) {
        int add = (t >= off) ? s[t - off] : 0;
        __syncthreads();
        s[t] += add;
        __syncthreads();
    }
    if (t < nb) bsum[t] = s[t] - v;          // exclusive block offsets
}

__global__ __launch_bounds__(256) void k_scan3(int* __restrict__ rp, const int* __restrict__ bsum) {
    int i = blockIdx.x * 256 + threadIdx.x;
    if (i < NN) rp[i] += bsum[i >> 8];
    if (i == 0) rp[NN] = NE;
}

__global__ __launch_bounds__(256) void k_fill(const int* __restrict__ ei, const int* __restrict__ rp,
                                              int* __restrict__ cursor, int* __restrict__ csr) {
    int e = blockIdx.x * 256 + threadIdx.x;
    if (e < NE) {
        int s = ei[e];
        int d = ei[NE + e];
        int p = atomicAdd(&cursor[d], 1);
        csr[rp[d] + p] = s;
    }
}

__global__ __launch_bounds__(256) void k_gstart(const int* __restrict__ batch, int* __restrict__ gstart) {
    int g = blockIdx.x * 256 + threadIdx.x;
    if (g > NG) return;
    int lo = 0, hi = NN;
    while (lo < hi) {
        int mid = (lo + hi) >> 1;
        if (batch[mid] < g) lo = mid + 1; else hi = mid;
    }
    gstart[g] = lo;
}

// ---------- dense compute ----------

// H = X(N x 11) @ W(11 x 128), 16 rows per block
__global__ __launch_bounds__(256) void k_gemm11(const float* __restrict__ X, const float* __restrict__ W,
                                                float* __restrict__ H) {
    __shared__ float Ws[FIN][HID];
    __shared__ float Xs[16][FIN + 1];
    int t = threadIdx.x;
    int row0 = blockIdx.x * 16;
    for (int idx = t; idx < FIN * HID; idx += 256) Ws[idx / HID][idx % HID] = W[idx];
    for (int idx = t; idx < 16 * FIN; idx += 256) {
        int lin = row0 * FIN + idx;
        Xs[idx / FIN][idx % FIN] = (lin < NN * FIN) ? X[lin] : 0.f;
    }
    __syncthreads();
    int c = t & (HID - 1);
    int rg = t >> 7;  // 0..1
    #pragma unroll
    for (int i = 0; i < 8; ++i) {
        int r = rg * 8 + i;
        int row = row0 + r;
        if (row < NN) {
            float a = 0.f;
            #pragma unroll
            for (int k = 0; k < FIN; ++k) a += Xs[r][k] * Ws[k][c];
            H[row * HID + c] = a;
        }
    }
}

// H = X(N x 128) @ W(128 x 128); BM=64, KT=32, 8x4 register tile
__global__ __launch_bounds__(256) void k_gemm128(const float* __restrict__ X, const float* __restrict__ W,
                                                 float* __restrict__ H) {
    __shared__ float Xs[64][33];
    __shared__ float Ws[32][132];
    int t = threadIdx.x;
    int row0 = blockIdx.x * 64;
    int tc = t & 31, tr = t >> 5;   // tc: col-group 0..31, tr: row-group 0..7
    float acc[8][4] = {};
    for (int kk = 0; kk < HID; kk += 32) {
        #pragma unroll
        for (int i = 0; i < 8; ++i) {
            int r = tr + 8 * i;  // load rows
            int row = row0 + r;
            Xs[r][tc] = (row < NN) ? X[row * HID + kk + tc] : 0.f;
        }
        int wc = t & 127, wr0 = t >> 7;
        #pragma unroll
        for (int i = 0; i < 16; ++i) {
            int r = wr0 * 16 + i;
            Ws[r][wc] = W[(kk + r) * HID + wc];
        }
        __syncthreads();
        #pragma unroll
        for (int k = 0; k < 32; ++k) {
            float xv[8];
            #pragma unroll
            for (int i = 0; i < 8; ++i) xv[i] = Xs[tr * 8 + i][k];
            float4 w4 = *(const float4*)&Ws[k][tc * 4];
            #pragma unroll
            for (int i = 0; i < 8; ++i) {
                acc[i][0] += xv[i] * w4.x;
                acc[i][1] += xv[i] * w4.y;
                acc[i][2] += xv[i] * w4.z;
                acc[i][3] += xv[i] * w4.w;
            }
        }
        __syncthreads();
    }
    #pragma unroll
    for (int i = 0; i < 8; ++i) {
        int row = row0 + tr * 8 + i;
        if (row < NN) {
            float4 o;
            o.x = acc[i][0]; o.y = acc[i][1]; o.z = acc[i][2]; o.w = acc[i][3];
            *(float4*)&H[row * HID + tc * 4] = o;
        }
    }
}

// out[v] = (relu?) dis_v * sum_{s in N(v)} dis_s*H[s] + H[v]/deg_v + bias ; one wave per node
__global__ __launch_bounds__(256) void k_agg(const float* __restrict__ H, const int* __restrict__ rp,
                                             const int* __restrict__ csr, const float* __restrict__ dis,
                                             const float* __restrict__ bias, float* __restrict__ out,
                                             int relu) {
    int wid = threadIdx.x >> 6;
    int lane = threadIdx.x & 63;
    int v = blockIdx.x * 4 + wid;
    if (v >= NN) return;
    int beg = rp[v], end = rp[v + 1];
    float a0 = 0.f, a1 = 0.f;
    for (int e = beg; e < end; ++e) {
        int s = csr[e];
        float w = dis[s];
        a0 += w * H[s * HID + lane];
        a1 += w * H[s * HID + 64 + lane];
    }
    float dv = dis[v];
    float sw = dv * dv;
    float r0 = dv * a0 + H[v * HID + lane] * sw + bias[lane];
    float r1 = dv * a1 + H[v * HID + 64 + lane] * sw + bias[64 + lane];
    if (relu) { r0 = fmaxf(r0, 0.f); r1 = fmaxf(r1, 0.f); }
    out[v * HID + lane] = r0;
    out[v * HID + 64 + lane] = r1;
}

// mean-pool per graph (batch sorted -> contiguous ranges); one wave per graph
__global__ __launch_bounds__(256) void k_pool(const float* __restrict__ H, const int* __restrict__ gstart,
                                              float* __restrict__ pooled) {
    int wid = threadIdx.x >> 6;
    int lane = threadIdx.x & 63;
    int g = blockIdx.x * 4 + wid;
    if (g >= NG) return;
    int beg = gstart[g], end = gstart[g + 1];
    float a0 = 0.f, a1 = 0.f;
    for (int n = beg; n < end; ++n) {
        a0 += H[n * HID + lane];
        a1 += H[n * HID + 64 + lane];
    }
    float inv = 1.f / fmaxf((float)(end - beg), 1.f);
    pooled[g * HID + lane] = a0 * inv;
    pooled[g * HID + 64 + lane] = a1 * inv;
}

__global__ __launch_bounds__(64) void k_linear(const float* __restrict__ P, const float* __restrict__ Wl,
                                               const float* __restrict__ bl, float* __restrict__ out) {
    int g = blockIdx.x;
    int t = threadIdx.x;
    __shared__ float ps[HID];
    for (int k = t; k < HID; k += 64) ps[k] = P[g * HID + k];
    __syncthreads();
    if (t < NC) {
        float a = bl[t];
        #pragma unroll 4
        for (int k = 0; k < HID; ++k) a += ps[k] * Wl[k * NC + t];
        out[g * NC + t] = a;
    }
}

// ---------- launch ----------

extern "C" void kernel_launch(void* const* d_in, const int* in_sizes, int n_in,
                              void* d_out, int out_size, void* d_ws, size_t ws_size,
                              hipStream_t stream) {
    const float* x   = (const float*)d_in[0];
    const int* ei    = (const int*)d_in[1];   // [2][NE] int32
    const int* batch = (const int*)d_in[2];
    const float* W1 = (const float*)d_in[3];
    const float* b1 = (const float*)d_in[4];
    const float* W2 = (const float*)d_in[5];
    const float* b2 = (const float*)d_in[6];
    const float* W3 = (const float*)d_in[7];
    const float* b3 = (const float*)d_in[8];
    const float* Wl = (const float*)d_in[9];
    const float* bl = (const float*)d_in[10];
    float* out = (float*)d_out;

    char* ws = (char*)d_ws;
    size_t off = 0;
    auto alloc = [&](size_t bytes) -> void* {
        void* p = ws + off;
        off += (bytes + 255) & ~(size_t)255;
        return p;
    };
    int*   deg    = (int*)alloc((size_t)NN * 4);
    float* dis    = (float*)alloc((size_t)NN * 4);
    int*   rp     = (int*)alloc((size_t)(NN + 1) * 4);
    int*   cursor = (int*)alloc((size_t)NN * 4);
    int*   csr    = (int*)alloc((size_t)NE * 4);
    int*   bsum   = (int*)alloc(512 * 4);
    int*   gstart = (int*)alloc((size_t)(NG + 1) * 4);
    float* bufA   = (float*)alloc((size_t)NN * HID * 4);
    float* bufB   = (float*)alloc((size_t)NN * HID * 4);
    float* pooled = (float*)alloc((size_t)NG * HID * 4);
    (void)ws_size; (void)in_sizes; (void)n_in; (void)out_size;

    hipMemsetAsync(deg, 0, (size_t)NN * 4, stream);
    hipMemsetAsync(cursor, 0, (size_t)NN * 4, stream);

    int eb  = (NE + 255) / 256;
    int nbv = (NN + 255) / 256;  // 391

    k_degree<<<eb, 256, 0, stream>>>(ei, deg);
    k_dis<<<nbv, 256, 0, stream>>>(deg, dis);
    k_scan1<<<nbv, 256, 0, stream>>>(deg, rp, bsum);
    k_scan2<<<1, 512, 0, stream>>>(bsum, nbv);
    k_scan3<<<nbv, 256, 0, stream>>>(rp, bsum);
    k_fill<<<eb, 256, 0, stream>>>(ei, rp, cursor, csr);
    k_gstart<<<(NG + 256) / 256, 256, 0, stream>>>(batch, gstart);

    k_gemm11<<<(NN + 15) / 16, 256, 0, stream>>>(x, W1, bufA);
    k_agg<<<(NN + 3) / 4, 256, 0, stream>>>(bufA, rp, csr, dis, b1, bufB, 1);
    k_gemm128<<<(NN + 63) / 64, 256, 0, stream>>>(bufB, W2, bufA);
    k_agg<<<(NN + 3) / 4, 256, 0, stream>>>(bufA, rp, csr, dis, b2, bufB, 1);
    k_gemm128<<<(NN + 63) / 64, 256, 0, stream>>>(bufB, W3, bufA);
    k_agg<<<(NN + 3) / 4, 256, 0, stream>>>(bufA, rp, csr, dis, b3, bufB, 0);

    k_pool<<<(NG + 3) / 4, 256, 0, stream>>>(bufB, gstart, pooled);
    k_linear<<<NG, 64, 0, stream>>>(pooled, Wl, bl, out);
}

// Round 2
// 574.957 us; speedup vs baseline: 1.5278x; 1.5278x over previous
//
#include <hip/hip_runtime.h>
#include <hip/hip_bf16.h>
#include <hip/hip_fp16.h>

#define NN 100000
#define NE 1600000
#define NG 5000
#define FIN 11
#define HID 128
#define NC 19

// ---------- graph preprocessing ----------

__global__ __launch_bounds__(256) void k_degree(const int* __restrict__ ei, int* __restrict__ deg) {
    int e = blockIdx.x * 256 + threadIdx.x;
    if (e < NE) atomicAdd(&deg[ei[NE + e]], 1);
}

__global__ __launch_bounds__(256) void k_dis(const int* __restrict__ deg, float* __restrict__ dis) {
    int v = blockIdx.x * 256 + threadIdx.x;
    if (v < NN) dis[v] = rsqrtf((float)deg[v] + 1.0f);
}

__global__ __launch_bounds__(256) void k_scan1(const int* __restrict__ deg, int* __restrict__ rp, int* __restrict__ bsum) {
    __shared__ int s[256];
    int t = threadIdx.x;
    int i = blockIdx.x * 256 + t;
    int v = (i < NN) ? deg[i] : 0;
    s[t] = v;
    __syncthreads();
    for (int off = 1; off < 256; off <<= 1) {
        int add = (t >= off) ? s[t - off] : 0;
        __syncthreads();
        s[t] += add;
        __syncthreads();
    }
    if (i < NN) rp[i] = s[t] - v;            // exclusive within block
    if (t == 255) bsum[blockIdx.x] = s[255]; // block total
}

__global__ __launch_bounds__(512) void k_scan2(int* __restrict__ bsum, int nb) {
    __shared__ int s[512];
    int t = threadIdx.x;
    int v = (t < nb) ? bsum[t] : 0;
    s[t] = v;
    __syncthreads();
    for (int off = 1; off < 512; off <<= 1) {
        int add = (t >= off) ? s[t - off] : 0;
        __syncthreads();
        s[t] += add;
        __syncthreads();
    }
    if (t < nb) bsum[t] = s[t] - v;          // exclusive block offsets
}

__global__ __launch_bounds__(256) void k_scan3(int* __restrict__ rp, const int* __restrict__ bsum) {
    int i = blockIdx.x * 256 + threadIdx.x;
    if (i < NN) rp[i] += bsum[i >> 8];
    if (i == 0) rp[NN] = NE;
}

__global__ __launch_bounds__(256) void k_fill(const int* __restrict__ ei, const int* __restrict__ rp,
                                              int* __restrict__ cursor, int* __restrict__ csr) {
    int e = blockIdx.x * 256 + threadIdx.x;
    if (e < NE) {
        int s = ei[e];
        int d = ei[NE + e];
        int p = atomicAdd(&cursor[d], 1);
        csr[rp[d] + p] = s;
    }
}

__global__ __launch_bounds__(256) void k_gstart(const int* __restrict__ batch, int* __restrict__ gstart) {
    int g = blockIdx.x * 256 + threadIdx.x;
    if (g > NG) return;
    int lo = 0, hi = NN;
    while (lo < hi) {
        int mid = (lo + hi) >> 1;
        if (batch[mid] < g) lo = mid + 1; else hi = mid;
    }
    gstart[g] = lo;
}

// xsc[v] = dis[v] * x[v]   (width 11)
__global__ __launch_bounds__(256) void k_prescale(const float* __restrict__ x, const float* __restrict__ dis,
                                                  float* __restrict__ xsc) {
    int i = blockIdx.x * 256 + threadIdx.x;
    if (i < NN * FIN) xsc[i] = x[i] * dis[i / FIN];
}

// ---------- aggregation ----------

// xa[v] = dis[v] * ( sum_{s in N(v)} xsc[s] + xsc[v] )   (width 11; 16 lanes per node)
__global__ __launch_bounds__(256) void k_agg11(const float* __restrict__ xsc, const int* __restrict__ rp,
                                               const int* __restrict__ csr, const float* __restrict__ dis,
                                               float* __restrict__ xa) {
    int t = threadIdx.x;
    int q = t >> 4;        // node slot in block (0..15)
    int c = t & 15;        // feature lane
    int v = blockIdx.x * 16 + q;
    if (v >= NN) return;
    bool act = c < FIN;
    float acc = 0.f;
    int beg = rp[v], end = rp[v + 1];
    for (int e = beg; e < end; ++e) {
        int s = csr[e];
        if (act) acc += xsc[s * FIN + c];
    }
    if (act) {
        acc += xsc[v * FIN + c];
        xa[v * FIN + c] = acc * dis[v];
    }
}

// t[v] = dis[v] * ( sum_{s in N(v)} Ht[s] + Ht[v] )  where Ht[u] = dis[u]*h[u] in fp16
__global__ __launch_bounds__(256) void k_agg16(const __half2* __restrict__ Ht, const int* __restrict__ rp,
                                               const int* __restrict__ csr, const float* __restrict__ dis,
                                               float* __restrict__ out) {
    int wid = threadIdx.x >> 6;
    int lane = threadIdx.x & 63;
    int v = blockIdx.x * 4 + wid;
    if (v >= NN) return;
    int beg = rp[v], end = rp[v + 1];
    float ax = 0.f, ay = 0.f;
    int e = beg;
    for (; e + 4 <= end; e += 4) {
        int s0 = csr[e], s1 = csr[e + 1], s2 = csr[e + 2], s3 = csr[e + 3];
        __half2 h0 = Ht[s0 * 64 + lane];
        __half2 h1 = Ht[s1 * 64 + lane];
        __half2 h2 = Ht[s2 * 64 + lane];
        __half2 h3 = Ht[s3 * 64 + lane];
        float2 f0 = __half22float2(h0), f1 = __half22float2(h1);
        float2 f2 = __half22float2(h2), f3 = __half22float2(h3);
        ax += (f0.x + f1.x) + (f2.x + f3.x);
        ay += (f0.y + f1.y) + (f2.y + f3.y);
    }
    for (; e < end; ++e) {
        int s = csr[e];
        float2 f = __half22float2(Ht[s * 64 + lane]);
        ax += f.x; ay += f.y;
    }
    float2 fs = __half22float2(Ht[v * 64 + lane]);   // self loop (prescaled)
    ax += fs.x; ay += fs.y;
    float dv = dis[v];
    float2 o;
    o.x = ax * dv;
    o.y = ay * dv;
    *(float2*)&out[v * HID + lane * 2] = o;
}

// ---------- dense compute ----------

// h1 = relu(xa(N x 11) @ W1(11 x 128) + b1); write Ht = fp16(dis*h1)
__global__ __launch_bounds__(256) void k_gemm11(const float* __restrict__ X, const float* __restrict__ W,
                                                const float* __restrict__ bias, const float* __restrict__ dis,
                                                __half* __restrict__ out16) {
    __shared__ float Ws[FIN][HID];
    __shared__ float Xs[16][FIN + 1];
    int t = threadIdx.x;
    int row0 = blockIdx.x * 16;
    for (int idx = t; idx < FIN * HID; idx += 256) Ws[idx / HID][idx % HID] = W[idx];
    for (int idx = t; idx < 16 * FIN; idx += 256) {
        int lin = row0 * FIN + idx;
        Xs[idx / FIN][idx % FIN] = (lin < NN * FIN) ? X[lin] : 0.f;
    }
    __syncthreads();
    int c = t & (HID - 1);
    int rg = t >> 7;  // 0..1
    #pragma unroll
    for (int i = 0; i < 8; ++i) {
        int r = rg * 8 + i;
        int row = row0 + r;
        if (row < NN) {
            float a = bias[c];
            #pragma unroll
            for (int k = 0; k < FIN; ++k) a += Xs[r][k] * Ws[k][c];
            a = fmaxf(a, 0.f);
            out16[row * HID + c] = __float2half(a * dis[row]);
        }
    }
}

// H = X(N x 128) @ W(128 x 128) + bias; optional relu; output either
// prescaled fp16 table (out16) or fp32 (out32, may alias X: block-private rows).
__global__ __launch_bounds__(256) void k_gemm128(const float* __restrict__ X, const float* __restrict__ W,
                                                 const float* __restrict__ bias, const float* __restrict__ dis,
                                                 __half2* __restrict__ out16, float* __restrict__ out32,
                                                 int relu) {
    __shared__ float Xs[64][33];
    __shared__ float Ws[32][132];
    int t = threadIdx.x;
    int row0 = blockIdx.x * 64;
    int tc = t & 31, tr = t >> 5;   // tc: col-group 0..31, tr: row-group 0..7
    float acc[8][4] = {};
    for (int kk = 0; kk < HID; kk += 32) {
        #pragma unroll
        for (int i = 0; i < 8; ++i) {
            int r = tr + 8 * i;
            int row = row0 + r;
            Xs[r][tc] = (row < NN) ? X[row * HID + kk + tc] : 0.f;
        }
        int wc = t & 127, wr0 = t >> 7;
        #pragma unroll
        for (int i = 0; i < 16; ++i) {
            int r = wr0 * 16 + i;
            Ws[r][wc] = W[(kk + r) * HID + wc];
        }
        __syncthreads();
        #pragma unroll
        for (int k = 0; k < 32; ++k) {
            float xv[8];
            #pragma unroll
            for (int i = 0; i < 8; ++i) xv[i] = Xs[tr * 8 + i][k];
            float4 w4 = *(const float4*)&Ws[k][tc * 4];
            #pragma unroll
            for (int i = 0; i < 8; ++i) {
                acc[i][0] += xv[i] * w4.x;
                acc[i][1] += xv[i] * w4.y;
                acc[i][2] += xv[i] * w4.z;
                acc[i][3] += xv[i] * w4.w;
            }
        }
        __syncthreads();
    }
    float4 bb = *(const float4*)&bias[tc * 4];
    #pragma unroll
    for (int i = 0; i < 8; ++i) {
        int row = row0 + tr * 8 + i;
        if (row < NN) {
            float4 o;
            o.x = acc[i][0] + bb.x;
            o.y = acc[i][1] + bb.y;
            o.z = acc[i][2] + bb.z;
            o.w = acc[i][3] + bb.w;
            if (relu) {
                o.x = fmaxf(o.x, 0.f); o.y = fmaxf(o.y, 0.f);
                o.z = fmaxf(o.z, 0.f); o.w = fmaxf(o.w, 0.f);
            }
            if (out16) {
                float d = dis[row];
                out16[row * 64 + tc * 2]     = __floats2half2_rn(o.x * d, o.y * d);
                out16[row * 64 + tc * 2 + 1] = __floats2half2_rn(o.z * d, o.w * d);
            } else {
                *(float4*)&out32[row * HID + tc * 4] = o;
            }
        }
    }
}

// mean-pool per graph (batch sorted -> contiguous ranges); one wave per graph
__global__ __launch_bounds__(256) void k_pool(const float* __restrict__ H, const int* __restrict__ gstart,
                                              float* __restrict__ pooled) {
    int wid = threadIdx.x >> 6;
    int lane = threadIdx.x & 63;
    int g = blockIdx.x * 4 + wid;
    if (g >= NG) return;
    int beg = gstart[g], end = gstart[g + 1];
    float a0 = 0.f, a1 = 0.f;
    for (int n = beg; n < end; ++n) {
        a0 += H[n * HID + lane];
        a1 += H[n * HID + 64 + lane];
    }
    float inv = 1.f / fmaxf((float)(end - beg), 1.f);
    pooled[g * HID + lane] = a0 * inv;
    pooled[g * HID + 64 + lane] = a1 * inv;
}

__global__ __launch_bounds__(64) void k_linear(const float* __restrict__ P, const float* __restrict__ Wl,
                                               const float* __restrict__ bl, float* __restrict__ out) {
    int g = blockIdx.x;
    int t = threadIdx.x;
    __shared__ float ps[HID];
    for (int k = t; k < HID; k += 64) ps[k] = P[g * HID + k];
    __syncthreads();
    if (t < NC) {
        float a = bl[t];
        #pragma unroll 4
        for (int k = 0; k < HID; ++k) a += ps[k] * Wl[k * NC + t];
        out[g * NC + t] = a;
    }
}

// ---------- launch ----------

extern "C" void kernel_launch(void* const* d_in, const int* in_sizes, int n_in,
                              void* d_out, int out_size, void* d_ws, size_t ws_size,
                              hipStream_t stream) {
    const float* x   = (const float*)d_in[0];
    const int* ei    = (const int*)d_in[1];   // [2][NE] int32
    const int* batch = (const int*)d_in[2];
    const float* W1 = (const float*)d_in[3];
    const float* b1 = (const float*)d_in[4];
    const float* W2 = (const float*)d_in[5];
    const float* b2 = (const float*)d_in[6];
    const float* W3 = (const float*)d_in[7];
    const float* b3 = (const float*)d_in[8];
    const float* Wl = (const float*)d_in[9];
    const float* bl = (const float*)d_in[10];
    float* out = (float*)d_out;

    char* ws = (char*)d_ws;
    size_t off = 0;
    auto alloc = [&](size_t bytes) -> void* {
        void* p = ws + off;
        off += (bytes + 255) & ~(size_t)255;
        return p;
    };
    int*     deg    = (int*)alloc((size_t)NN * 4);
    float*   dis    = (float*)alloc((size_t)NN * 4);
    int*     rp     = (int*)alloc((size_t)(NN + 1) * 4);
    int*     cursor = (int*)alloc((size_t)NN * 4);
    int*     csr    = (int*)alloc((size_t)NE * 4);
    int*     bsum   = (int*)alloc(512 * 4);
    int*     gstart = (int*)alloc((size_t)(NG + 1) * 4);
    float*   xsc    = (float*)alloc((size_t)NN * FIN * 4);
    float*   xa     = (float*)alloc((size_t)NN * FIN * 4);
    __half2* Ht     = (__half2*)alloc((size_t)NN * HID * 2);
    float*   tbuf   = (float*)alloc((size_t)NN * HID * 4);
    float*   pooled = (float*)alloc((size_t)NG * HID * 4);
    (void)ws_size; (void)in_sizes; (void)n_in; (void)out_size;

    hipMemsetAsync(deg, 0, (size_t)NN * 4, stream);
    hipMemsetAsync(cursor, 0, (size_t)NN * 4, stream);

    int eb  = (NE + 255) / 256;
    int nbv = (NN + 255) / 256;  // 391

    k_degree<<<eb, 256, 0, stream>>>(ei, deg);
    k_dis<<<nbv, 256, 0, stream>>>(deg, dis);
    k_scan1<<<nbv, 256, 0, stream>>>(deg, rp, bsum);
    k_scan2<<<1, 512, 0, stream>>>(bsum, nbv);
    k_scan3<<<nbv, 256, 0, stream>>>(rp, bsum);
    k_fill<<<eb, 256, 0, stream>>>(ei, rp, cursor, csr);
    k_gstart<<<(NG + 256) / 256, 256, 0, stream>>>(batch, gstart);
    k_prescale<<<(NN * FIN + 255) / 256, 256, 0, stream>>>(x, dis, xsc);

    // layer 1: aggregate width-11, then GEMM (+bias+relu+fp16 prescale)
    k_agg11<<<(NN + 15) / 16, 256, 0, stream>>>(xsc, rp, csr, dis, xa);
    k_gemm11<<<(NN + 15) / 16, 256, 0, stream>>>(xa, W1, b1, dis, (__half*)Ht);

    // layer 2: aggregate fp16 table, GEMM (+bias+relu+fp16 prescale)
    k_agg16<<<(NN + 3) / 4, 256, 0, stream>>>(Ht, rp, csr, dis, tbuf);
    k_gemm128<<<(NN + 63) / 64, 256, 0, stream>>>(tbuf, W2, b2, dis, Ht, nullptr, 1);

    // layer 3: aggregate fp16 table, GEMM (+bias, fp32, in-place on tbuf)
    k_agg16<<<(NN + 3) / 4, 256, 0, stream>>>(Ht, rp, csr, dis, tbuf);
    k_gemm128<<<(NN + 63) / 64, 256, 0, stream>>>(tbuf, W3, b3, nullptr, nullptr, tbuf, 0);

    k_pool<<<(NG + 3) / 4, 256, 0, stream>>>(tbuf, gstart, pooled);
    k_linear<<<NG, 64, 0, stream>>>(pooled, Wl, bl, out);
}

// Round 3
// 516.576 us; speedup vs baseline: 1.7005x; 1.1130x over previous
//
#include <hip/hip_runtime.h>
#include <hip/hip_bf16.h>
#include <hip/hip_fp16.h>

#define NN 100000
#define NE 1600000
#define NG 5000
#define FIN 11
#define HID 128
#define NC 19

#define NBK 98           // ceil(NN / 1024) buckets for CSR build
#define BKSH 10          // bucket = dst >> 10
#define BKMASK 1023

// ---------- graph preprocessing ----------

__global__ __launch_bounds__(256) void k_degree(const int* __restrict__ ei, int* __restrict__ deg) {
    int e = blockIdx.x * 256 + threadIdx.x;
    if (e < NE) atomicAdd(&deg[ei[NE + e]], 1);
}

__global__ __launch_bounds__(256) void k_dis(const int* __restrict__ deg, float* __restrict__ dis) {
    int v = blockIdx.x * 256 + threadIdx.x;
    if (v < NN) dis[v] = rsqrtf((float)deg[v] + 1.0f);
}

__global__ __launch_bounds__(256) void k_scan1(const int* __restrict__ deg, int* __restrict__ rp, int* __restrict__ bsum) {
    __shared__ int s[256];
    int t = threadIdx.x;
    int i = blockIdx.x * 256 + t;
    int v = (i < NN) ? deg[i] : 0;
    s[t] = v;
    __syncthreads();
    for (int off = 1; off < 256; off <<= 1) {
        int add = (t >= off) ? s[t - off] : 0;
        __syncthreads();
        s[t] += add;
        __syncthreads();
    }
    if (i < NN) rp[i] = s[t] - v;
    if (t == 255) bsum[blockIdx.x] = s[255];
}

__global__ __launch_bounds__(512) void k_scan2(int* __restrict__ bsum, int nb) {
    __shared__ int s[512];
    int t = threadIdx.x;
    int v = (t < nb) ? bsum[t] : 0;
    s[t] = v;
    __syncthreads();
    for (int off = 1; off < 512; off <<= 1) {
        int add = (t >= off) ? s[t - off] : 0;
        __syncthreads();
        s[t] += add;
        __syncthreads();
    }
    if (t < nb) bsum[t] = s[t] - v;
}

__global__ __launch_bounds__(256) void k_scan3(int* __restrict__ rp, const int* __restrict__ bsum) {
    int i = blockIdx.x * 256 + threadIdx.x;
    if (i < NN) rp[i] += bsum[i >> 8];
    if (i == 0) rp[NN] = NE;
}

// Pass 1: bin edges by dst>>10 into bucket-major scratch with block-contiguous runs.
// pack = src (17b) | dst_low10 << 17
__global__ __launch_bounds__(1024) void k_p1scatter(const int* __restrict__ ei, const int* __restrict__ rp,
                                                    int* __restrict__ gcur, unsigned int* __restrict__ p1) {
    __shared__ int hist[NBK];
    __shared__ int base[NBK];
    __shared__ int lrank[NBK];
    int t = threadIdx.x;
    if (t < NBK) { hist[t] = 0; lrank[t] = 0; }
    __syncthreads();

    int e0 = blockIdx.x * 4096;
    int sr[4], dr[4], bk[4];
    #pragma unroll
    for (int k = 0; k < 4; ++k) {
        int e = e0 + k * 1024 + t;
        if (e < NE) {
            sr[k] = ei[e];
            dr[k] = ei[NE + e];
            bk[k] = dr[k] >> BKSH;
            atomicAdd(&hist[bk[k]], 1);
        } else bk[k] = -1;
    }
    __syncthreads();
    if (t < NBK && hist[t] > 0)
        base[t] = rp[t << BKSH] + atomicAdd(&gcur[t], hist[t]);
    __syncthreads();
    #pragma unroll
    for (int k = 0; k < 4; ++k) {
        if (bk[k] >= 0) {
            int slot = atomicAdd(&lrank[bk[k]], 1);
            p1[base[bk[k]] + slot] = (unsigned int)sr[k] | ((unsigned int)(dr[k] & BKMASK) << 17);
        }
    }
}

// Pass 2: one block per bucket; exact per-node placement inside private CSR window.
__global__ __launch_bounds__(1024) void k_p2fill(const unsigned int* __restrict__ p1, const int* __restrict__ rp,
                                                 int* __restrict__ csr) {
    __shared__ int rpl[1025];
    __shared__ int cur[1024];
    int bkt = blockIdx.x;
    int t = threadIdx.x;
    int v0 = bkt << BKSH;
    int nb = NN - v0; if (nb > 1024) nb = 1024;
    for (int i = t; i <= nb; i += 1024) rpl[i] = rp[v0 + i];
    cur[t] = 0;
    __syncthreads();
    int b0 = rpl[0];
    int ne = rpl[nb] - b0;
    for (int i = t; i < ne; i += 1024) {
        unsigned int u = p1[b0 + i];
        int s = (int)(u & 0x1FFFFu);
        int dl = (int)(u >> 17);
        int off = atomicAdd(&cur[dl], 1);
        csr[rpl[dl] + off] = s;
    }
}

__global__ __launch_bounds__(256) void k_gstart(const int* __restrict__ batch, int* __restrict__ gstart) {
    int g = blockIdx.x * 256 + threadIdx.x;
    if (g > NG) return;
    int lo = 0, hi = NN;
    while (lo < hi) {
        int mid = (lo + hi) >> 1;
        if (batch[mid] < g) lo = mid + 1; else hi = mid;
    }
    gstart[g] = lo;
}

// xsc[v] = dis[v] * x[v]   (width 11)
__global__ __launch_bounds__(256) void k_prescale(const float* __restrict__ x, const float* __restrict__ dis,
                                                  float* __restrict__ xsc) {
    int i = blockIdx.x * 256 + threadIdx.x;
    if (i < NN * FIN) xsc[i] = x[i] * dis[i / FIN];
}

// ---------- aggregation ----------

// xa[v] = dis[v] * ( sum_{s in N(v)} xsc[s] + xsc[v] )   (width 11; 16 lanes per node)
__global__ __launch_bounds__(256) void k_agg11(const float* __restrict__ xsc, const int* __restrict__ rp,
                                               const int* __restrict__ csr, const float* __restrict__ dis,
                                               float* __restrict__ xa) {
    int t = threadIdx.x;
    int q = t >> 4;
    int c = t & 15;
    int v = blockIdx.x * 16 + q;
    if (v >= NN) return;
    bool act = c < FIN;
    float acc = 0.f;
    int beg = rp[v], end = rp[v + 1];
    for (int e = beg; e < end; ++e) {
        int s = csr[e];
        if (act) acc += xsc[s * FIN + c];
    }
    if (act) {
        acc += xsc[v * FIN + c];
        xa[v * FIN + c] = acc * dis[v];
    }
}

// out16[v] = fp16( dis[v] * ( sum_{s in N(v)} Ht[s] + Ht[v] ) )
__global__ __launch_bounds__(256) void k_agg16(const __half2* __restrict__ Ht, const int* __restrict__ rp,
                                               const int* __restrict__ csr, const float* __restrict__ dis,
                                               __half2* __restrict__ out16) {
    int wid = threadIdx.x >> 6;
    int lane = threadIdx.x & 63;
    int v = blockIdx.x * 4 + wid;
    if (v >= NN) return;
    int beg = rp[v], end = rp[v + 1];
    float ax = 0.f, ay = 0.f;
    int e = beg;
    for (; e + 8 <= end; e += 8) {
        int s[8];
        #pragma unroll
        for (int k = 0; k < 8; ++k) s[k] = csr[e + k];
        float2 f[8];
        #pragma unroll
        for (int k = 0; k < 8; ++k) f[k] = __half22float2(Ht[s[k] * 64 + lane]);
        #pragma unroll
        for (int k = 0; k < 8; ++k) { ax += f[k].x; ay += f[k].y; }
    }
    for (; e < end; ++e) {
        int s = csr[e];
        float2 f = __half22float2(Ht[s * 64 + lane]);
        ax += f.x; ay += f.y;
    }
    float2 fs = __half22float2(Ht[v * 64 + lane]);
    ax += fs.x; ay += fs.y;
    float dv = dis[v];
    out16[v * 64 + lane] = __floats2half2_rn(ax * dv, ay * dv);
}

// ---------- dense compute ----------

// h1 = relu(xa(N x 11) @ W1(11 x 128) + b1); write Ht = fp16(dis*h1)
__global__ __launch_bounds__(256) void k_gemm11(const float* __restrict__ X, const float* __restrict__ W,
                                                const float* __restrict__ bias, const float* __restrict__ dis,
                                                __half* __restrict__ out16) {
    __shared__ float Ws[FIN][HID];
    __shared__ float Xs[16][FIN + 1];
    int t = threadIdx.x;
    int row0 = blockIdx.x * 16;
    for (int idx = t; idx < FIN * HID; idx += 256) Ws[idx / HID][idx % HID] = W[idx];
    for (int idx = t; idx < 16 * FIN; idx += 256) {
        int lin = row0 * FIN + idx;
        Xs[idx / FIN][idx % FIN] = (lin < NN * FIN) ? X[lin] : 0.f;
    }
    __syncthreads();
    int c = t & (HID - 1);
    int rg = t >> 7;
    #pragma unroll
    for (int i = 0; i < 8; ++i) {
        int r = rg * 8 + i;
        int row = row0 + r;
        if (row < NN) {
            float a = bias[c];
            #pragma unroll
            for (int k = 0; k < FIN; ++k) a += Xs[r][k] * Ws[k][c];
            a = fmaxf(a, 0.f);
            out16[row * HID + c] = __float2half(a * dis[row]);
        }
    }
}

// H = X16(N x 128 fp16) @ W(128 x 128) + bias
// mode 0: relu, write fp16 prescaled table (out16)
// mode 1: no relu, atomically accumulate per-graph sums into pooled
__global__ __launch_bounds__(256) void k_gemm128(const __half2* __restrict__ X2, const float* __restrict__ W,
                                                 const float* __restrict__ bias, const float* __restrict__ dis,
                                                 __half2* __restrict__ out16, float* __restrict__ pooled,
                                                 const int* __restrict__ batch, int mode) {
    __shared__ float Xs[64][33];
    __shared__ float Ws[32][132];
    int t = threadIdx.x;
    int row0 = blockIdx.x * 64;
    int tc = t & 31, tr = t >> 5;
    float acc[8][4] = {};
    for (int kk = 0; kk < HID; kk += 32) {
        #pragma unroll
        for (int j = 0; j < 4; ++j) {
            int idx = j * 256 + t;       // 0..1023
            int r = idx >> 4;            // tile row
            int cp = idx & 15;           // h2 pair within 32-col slab
            int row = row0 + r;
            float2 f = (row < NN) ? __half22float2(X2[row * 64 + (kk >> 1) + cp])
                                  : make_float2(0.f, 0.f);
            Xs[r][2 * cp] = f.x;
            Xs[r][2 * cp + 1] = f.y;
        }
        int wc = t & 127, wr0 = t >> 7;
        #pragma unroll
        for (int i = 0; i < 16; ++i) {
            int r = wr0 * 16 + i;
            Ws[r][wc] = W[(kk + r) * HID + wc];
        }
        __syncthreads();
        #pragma unroll
        for (int k = 0; k < 32; ++k) {
            float xv[8];
            #pragma unroll
            for (int i = 0; i < 8; ++i) xv[i] = Xs[tr * 8 + i][k];
            float4 w4 = *(const float4*)&Ws[k][tc * 4];
            #pragma unroll
            for (int i = 0; i < 8; ++i) {
                acc[i][0] += xv[i] * w4.x;
                acc[i][1] += xv[i] * w4.y;
                acc[i][2] += xv[i] * w4.z;
                acc[i][3] += xv[i] * w4.w;
            }
        }
        __syncthreads();
    }
    float4 bb = *(const float4*)&bias[tc * 4];
    if (mode == 0) {
        #pragma unroll
        for (int i = 0; i < 8; ++i) {
            int row = row0 + tr * 8 + i;
            if (row < NN) {
                float ox = fmaxf(acc[i][0] + bb.x, 0.f);
                float oy = fmaxf(acc[i][1] + bb.y, 0.f);
                float oz = fmaxf(acc[i][2] + bb.z, 0.f);
                float ow = fmaxf(acc[i][3] + bb.w, 0.f);
                float d = dis[row];
                out16[row * 64 + tc * 2]     = __floats2half2_rn(ox * d, oy * d);
                out16[row * 64 + tc * 2 + 1] = __floats2half2_rn(oz * d, ow * d);
            }
        }
    } else {
        // fused mean-pool numerator: run-length group rows by graph id
        int i = 0;
        while (i < 8) {
            int row = row0 + tr * 8 + i;
            if (row >= NN) break;
            int g = batch[row];
            float sx = acc[i][0] + bb.x, sy = acc[i][1] + bb.y;
            float sz = acc[i][2] + bb.z, sw = acc[i][3] + bb.w;
            int j = i + 1;
            while (j < 8) {
                int r2 = row0 + tr * 8 + j;
                if (r2 < NN && batch[r2] == g) {
                    sx += acc[j][0] + bb.x; sy += acc[j][1] + bb.y;
                    sz += acc[j][2] + bb.z; sw += acc[j][3] + bb.w;
                    ++j;
                } else break;
            }
            float* p = &pooled[g * HID + tc * 4];
            atomicAdd(p + 0, sx);
            atomicAdd(p + 1, sy);
            atomicAdd(p + 2, sz);
            atomicAdd(p + 3, sw);
            i = j;
        }
    }
}

// logits = (pooled_sums / cnt) @ Wlin + blin
__global__ __launch_bounds__(64) void k_linear(const float* __restrict__ P, const int* __restrict__ gstart,
                                               const float* __restrict__ Wl, const float* __restrict__ bl,
                                               float* __restrict__ out) {
    int g = blockIdx.x;
    int t = threadIdx.x;
    __shared__ float ps[HID];
    float inv = 1.f / fmaxf((float)(gstart[g + 1] - gstart[g]), 1.f);
    for (int k = t; k < HID; k += 64) ps[k] = P[g * HID + k] * inv;
    __syncthreads();
    if (t < NC) {
        float a = bl[t];
        #pragma unroll 4
        for (int k = 0; k < HID; ++k) a += ps[k] * Wl[k * NC + t];
        out[g * NC + t] = a;
    }
}

// ---------- launch ----------

extern "C" void kernel_launch(void* const* d_in, const int* in_sizes, int n_in,
                              void* d_out, int out_size, void* d_ws, size_t ws_size,
                              hipStream_t stream) {
    const float* x   = (const float*)d_in[0];
    const int* ei    = (const int*)d_in[1];
    const int* batch = (const int*)d_in[2];
    const float* W1 = (const float*)d_in[3];
    const float* b1 = (const float*)d_in[4];
    const float* W2 = (const float*)d_in[5];
    const float* b2 = (const float*)d_in[6];
    const float* W3 = (const float*)d_in[7];
    const float* b3 = (const float*)d_in[8];
    const float* Wl = (const float*)d_in[9];
    const float* bl = (const float*)d_in[10];
    float* out = (float*)d_out;

    char* ws = (char*)d_ws;
    size_t off = 0;
    auto alloc = [&](size_t bytes) -> void* {
        void* p = ws + off;
        off += (bytes + 255) & ~(size_t)255;
        return p;
    };
    int*          deg    = (int*)alloc((size_t)NN * 4);
    float*        dis    = (float*)alloc((size_t)NN * 4);
    int*          rp     = (int*)alloc((size_t)(NN + 1) * 4);
    int*          csr    = (int*)alloc((size_t)NE * 4);
    unsigned int* p1     = (unsigned int*)alloc((size_t)NE * 4);
    int*          gcur   = (int*)alloc(NBK * 4);
    int*          bsum   = (int*)alloc(512 * 4);
    int*          gstart = (int*)alloc((size_t)(NG + 1) * 4);
    float*        xsc    = (float*)alloc((size_t)NN * FIN * 4);
    float*        xa     = (float*)alloc((size_t)NN * FIN * 4);
    __half2*      Ht     = (__half2*)alloc((size_t)NN * HID * 2);
    __half2*      tb16   = (__half2*)alloc((size_t)NN * HID * 2);
    float*        pooled = (float*)alloc((size_t)NG * HID * 4);
    (void)ws_size; (void)in_sizes; (void)n_in; (void)out_size;

    hipMemsetAsync(deg, 0, (size_t)NN * 4, stream);
    hipMemsetAsync(gcur, 0, NBK * 4, stream);
    hipMemsetAsync(pooled, 0, (size_t)NG * HID * 4, stream);

    int eb  = (NE + 255) / 256;
    int nbv = (NN + 255) / 256;

    k_degree<<<eb, 256, 0, stream>>>(ei, deg);
    k_dis<<<nbv, 256, 0, stream>>>(deg, dis);
    k_scan1<<<nbv, 256, 0, stream>>>(deg, rp, bsum);
    k_scan2<<<1, 512, 0, stream>>>(bsum, nbv);
    k_scan3<<<nbv, 256, 0, stream>>>(rp, bsum);
    k_p1scatter<<<(NE + 4095) / 4096, 1024, 0, stream>>>(ei, rp, gcur, p1);
    k_p2fill<<<NBK, 1024, 0, stream>>>(p1, rp, csr);
    k_gstart<<<(NG + 256) / 256, 256, 0, stream>>>(batch, gstart);
    k_prescale<<<(NN * FIN + 255) / 256, 256, 0, stream>>>(x, dis, xsc);

    // layer 1
    k_agg11<<<(NN + 15) / 16, 256, 0, stream>>>(xsc, rp, csr, dis, xa);
    k_gemm11<<<(NN + 15) / 16, 256, 0, stream>>>(xa, W1, b1, dis, (__half*)Ht);

    // layer 2
    k_agg16<<<(NN + 3) / 4, 256, 0, stream>>>(Ht, rp, csr, dis, tb16);
    k_gemm128<<<(NN + 63) / 64, 256, 0, stream>>>(tb16, W2, b2, dis, Ht, nullptr, nullptr, 0);

    // layer 3 (+ fused mean-pool numerator)
    k_agg16<<<(NN + 3) / 4, 256, 0, stream>>>(Ht, rp, csr, dis, tb16);
    k_gemm128<<<(NN + 63) / 64, 256, 0, stream>>>(tb16, W3, b3, nullptr, nullptr, pooled, batch, 1);

    k_linear<<<NG, 64, 0, stream>>>(pooled, gstart, Wl, bl, out);
}

// Round 4
// 425.731 us; speedup vs baseline: 2.0633x; 1.2134x over previous
//
#include <hip/hip_runtime.h>
#include <hip/hip_bf16.h>
#include <hip/hip_fp16.h>

#define NN 100000
#define NE 1600000
#define NG 5000
#define FIN 11
#define HID 128
#define NC 19

#define NBK 98           // ceil(NN / 1024) buckets for CSR build
#define BKSH 10          // bucket = dst >> 10
#define BKMASK 1023

typedef _Float16 f16x8 __attribute__((ext_vector_type(8)));
typedef float f32x4 __attribute__((ext_vector_type(4)));

// ---------- graph preprocessing ----------

__global__ __launch_bounds__(256) void k_degree(const int* __restrict__ ei, int* __restrict__ deg) {
    int e = blockIdx.x * 256 + threadIdx.x;
    if (e < NE) atomicAdd(&deg[ei[NE + e]], 1);
}

__global__ __launch_bounds__(256) void k_dis(const int* __restrict__ deg, float* __restrict__ dis) {
    int v = blockIdx.x * 256 + threadIdx.x;
    if (v < NN) dis[v] = rsqrtf((float)deg[v] + 1.0f);
}

__global__ __launch_bounds__(256) void k_scan1(const int* __restrict__ deg, int* __restrict__ rp, int* __restrict__ bsum) {
    __shared__ int s[256];
    int t = threadIdx.x;
    int i = blockIdx.x * 256 + t;
    int v = (i < NN) ? deg[i] : 0;
    s[t] = v;
    __syncthreads();
    for (int off = 1; off < 256; off <<= 1) {
        int add = (t >= off) ? s[t - off] : 0;
        __syncthreads();
        s[t] += add;
        __syncthreads();
    }
    if (i < NN) rp[i] = s[t] - v;
    if (t == 255) bsum[blockIdx.x] = s[255];
}

__global__ __launch_bounds__(512) void k_scan2(int* __restrict__ bsum, int nb) {
    __shared__ int s[512];
    int t = threadIdx.x;
    int v = (t < nb) ? bsum[t] : 0;
    s[t] = v;
    __syncthreads();
    for (int off = 1; off < 512; off <<= 1) {
        int add = (t >= off) ? s[t - off] : 0;
        __syncthreads();
        s[t] += add;
        __syncthreads();
    }
    if (t < nb) bsum[t] = s[t] - v;
}

__global__ __launch_bounds__(256) void k_scan3(int* __restrict__ rp, const int* __restrict__ bsum) {
    int i = blockIdx.x * 256 + threadIdx.x;
    if (i < NN) rp[i] += bsum[i >> 8];
    if (i == 0) rp[NN] = NE;
}

// Pass 1: bin edges by dst>>10 into bucket-major scratch with block-contiguous runs.
__global__ __launch_bounds__(1024) void k_p1scatter(const int* __restrict__ ei, const int* __restrict__ rp,
                                                    int* __restrict__ gcur, unsigned int* __restrict__ p1) {
    __shared__ int hist[NBK];
    __shared__ int base[NBK];
    __shared__ int lrank[NBK];
    int t = threadIdx.x;
    if (t < NBK) { hist[t] = 0; lrank[t] = 0; }
    __syncthreads();

    int e0 = blockIdx.x * 4096;
    int sr[4], dr[4], bk[4];
    #pragma unroll
    for (int k = 0; k < 4; ++k) {
        int e = e0 + k * 1024 + t;
        if (e < NE) {
            sr[k] = ei[e];
            dr[k] = ei[NE + e];
            bk[k] = dr[k] >> BKSH;
            atomicAdd(&hist[bk[k]], 1);
        } else bk[k] = -1;
    }
    __syncthreads();
    if (t < NBK && hist[t] > 0)
        base[t] = rp[t << BKSH] + atomicAdd(&gcur[t], hist[t]);
    __syncthreads();
    #pragma unroll
    for (int k = 0; k < 4; ++k) {
        if (bk[k] >= 0) {
            int slot = atomicAdd(&lrank[bk[k]], 1);
            p1[base[bk[k]] + slot] = (unsigned int)sr[k] | ((unsigned int)(dr[k] & BKMASK) << 17);
        }
    }
}

// Pass 2: one block per bucket; exact per-node placement inside private CSR window.
__global__ __launch_bounds__(1024) void k_p2fill(const unsigned int* __restrict__ p1, const int* __restrict__ rp,
                                                 int* __restrict__ csr) {
    __shared__ int rpl[1025];
    __shared__ int cur[1024];
    int bkt = blockIdx.x;
    int t = threadIdx.x;
    int v0 = bkt << BKSH;
    int nb = NN - v0; if (nb > 1024) nb = 1024;
    for (int i = t; i <= nb; i += 1024) rpl[i] = rp[v0 + i];
    cur[t] = 0;
    __syncthreads();
    int b0 = rpl[0];
    int ne = rpl[nb] - b0;
    for (int i = t; i < ne; i += 1024) {
        unsigned int u = p1[b0 + i];
        int s = (int)(u & 0x1FFFFu);
        int dl = (int)(u >> 17);
        int off = atomicAdd(&cur[dl], 1);
        csr[rpl[dl] + off] = s;
    }
}

__global__ __launch_bounds__(256) void k_gstart(const int* __restrict__ batch, int* __restrict__ gstart) {
    int g = blockIdx.x * 256 + threadIdx.x;
    if (g > NG) return;
    int lo = 0, hi = NN;
    while (lo < hi) {
        int mid = (lo + hi) >> 1;
        if (batch[mid] < g) lo = mid + 1; else hi = mid;
    }
    gstart[g] = lo;
}

// xsc[v] = dis[v] * x[v]   (width 11)
__global__ __launch_bounds__(256) void k_prescale(const float* __restrict__ x, const float* __restrict__ dis,
                                                  float* __restrict__ xsc) {
    int i = blockIdx.x * 256 + threadIdx.x;
    if (i < NN * FIN) xsc[i] = x[i] * dis[i / FIN];
}

// pack W(128x128 fp32, k-major) into fp16 MFMA B-fragment order:
// Wp[slot*8+e], slot = (kb*8+ct)*64+lane, value = W[kb*32+(lane>>4)*8+e][ct*16+(lane&15)]
__global__ __launch_bounds__(256) void k_packW(const float* __restrict__ W, _Float16* __restrict__ Wp) {
    int t = blockIdx.x * 256 + threadIdx.x;
    if (t >= 2048) return;
    int lane = t & 63;
    int tile = t >> 6;
    int kb = tile >> 3, ct = tile & 7;
    int kbase = kb * 32 + (lane >> 4) * 8;
    int col = ct * 16 + (lane & 15);
    f16x8 v;
    #pragma unroll
    for (int e = 0; e < 8; ++e) v[e] = (_Float16)W[(kbase + e) * HID + col];
    *(f16x8*)&Wp[(size_t)t * 8] = v;
}

// ---------- aggregation ----------

// xa[v] = dis[v] * ( sum_{s in N(v)} xsc[s] + xsc[v] )   (width 11; 16 lanes per node)
__global__ __launch_bounds__(256) void k_agg11(const float* __restrict__ xsc, const int* __restrict__ rp,
                                               const int* __restrict__ csr, const float* __restrict__ dis,
                                               float* __restrict__ xa) {
    int t = threadIdx.x;
    int q = t >> 4;
    int c = t & 15;
    int v = blockIdx.x * 16 + q;
    if (v >= NN) return;
    bool act = c < FIN;
    float acc = 0.f;
    int beg = rp[v], end = rp[v + 1];
    for (int e = beg; e < end; ++e) {
        int s = csr[e];
        if (act) acc += xsc[s * FIN + c];
    }
    if (act) {
        acc += xsc[v * FIN + c];
        xa[v * FIN + c] = acc * dis[v];
    }
}

// out16[v] = fp16( dis[v] * ( sum_{s in N(v)} Ht[s] + Ht[v] ) )
__global__ __launch_bounds__(256) void k_agg16(const __half2* __restrict__ Ht, const int* __restrict__ rp,
                                               const int* __restrict__ csr, const float* __restrict__ dis,
                                               __half2* __restrict__ out16) {
    int wid = threadIdx.x >> 6;
    int lane = threadIdx.x & 63;
    int v = blockIdx.x * 4 + wid;
    if (v >= NN) return;
    int beg = rp[v], end = rp[v + 1];
    float ax = 0.f, ay = 0.f;
    int e = beg;
    for (; e + 8 <= end; e += 8) {
        int s[8];
        #pragma unroll
        for (int k = 0; k < 8; ++k) s[k] = csr[e + k];
        float2 f[8];
        #pragma unroll
        for (int k = 0; k < 8; ++k) f[k] = __half22float2(Ht[s[k] * 64 + lane]);
        #pragma unroll
        for (int k = 0; k < 8; ++k) { ax += f[k].x; ay += f[k].y; }
    }
    for (; e < end; ++e) {
        int s = csr[e];
        float2 f = __half22float2(Ht[s * 64 + lane]);
        ax += f.x; ay += f.y;
    }
    float2 fs = __half22float2(Ht[v * 64 + lane]);
    ax += fs.x; ay += fs.y;
    float dv = dis[v];
    out16[v * 64 + lane] = __floats2half2_rn(ax * dv, ay * dv);
}

// ---------- dense compute ----------

// h1 = relu(xa(N x 11) @ W1(11 x 128) + b1); write Ht = fp16(dis*h1)
__global__ __launch_bounds__(256) void k_gemm11(const float* __restrict__ X, const float* __restrict__ W,
                                                const float* __restrict__ bias, const float* __restrict__ dis,
                                                __half* __restrict__ out16) {
    __shared__ float Ws[FIN][HID];
    __shared__ float Xs[16][FIN + 1];
    int t = threadIdx.x;
    int row0 = blockIdx.x * 16;
    for (int idx = t; idx < FIN * HID; idx += 256) Ws[idx / HID][idx % HID] = W[idx];
    for (int idx = t; idx < 16 * FIN; idx += 256) {
        int lin = row0 * FIN + idx;
        Xs[idx / FIN][idx % FIN] = (lin < NN * FIN) ? X[lin] : 0.f;
    }
    __syncthreads();
    int c = t & (HID - 1);
    int rg = t >> 7;
    #pragma unroll
    for (int i = 0; i < 8; ++i) {
        int r = rg * 8 + i;
        int row = row0 + r;
        if (row < NN) {
            float a = bias[c];
            #pragma unroll
            for (int k = 0; k < FIN; ++k) a += Xs[r][k] * Ws[k][c];
            a = fmaxf(a, 0.f);
            out16[row * HID + c] = __float2half(a * dis[row]);
        }
    }
}

// MFMA GEMM: out(N x 128) = X16(N x 128) @ W(128 x 128) + bias
// mode 0: relu, out = fp16(dis * h)   (prescaled table for next agg)
// mode 1: out = fp16(h)               (h3 for pooling)
// Block: 256 thr = 4 waves, 32 rows/wave (2 slabs of 16), 128 rows/block.
__global__ __launch_bounds__(256) void k_gemm128m(const _Float16* __restrict__ X,
                                                  const _Float16* __restrict__ Wp,
                                                  const float* __restrict__ bias,
                                                  const float* __restrict__ dis,
                                                  _Float16* __restrict__ out, int mode) {
    int wave = threadIdx.x >> 6, lane = threadIdx.x & 63;
    int row0 = blockIdx.x * 128 + wave * 32;
    int rA = lane & 15, kg = lane >> 4;

    f32x4 acc[2][8];
    #pragma unroll
    for (int s = 0; s < 2; ++s)
        #pragma unroll
        for (int c = 0; c < 8; ++c)
            acc[s][c] = {0.f, 0.f, 0.f, 0.f};

    int r0c = row0 + rA;      if (r0c > NN - 1) r0c = NN - 1;
    int r1c = row0 + 16 + rA; if (r1c > NN - 1) r1c = NN - 1;
    const _Float16* xp0 = X + (size_t)r0c * HID + kg * 8;
    const _Float16* xp1 = X + (size_t)r1c * HID + kg * 8;

    #pragma unroll
    for (int kb = 0; kb < 4; ++kb) {
        f16x8 a0 = *(const f16x8*)(xp0 + kb * 32);
        f16x8 a1 = *(const f16x8*)(xp1 + kb * 32);
        #pragma unroll
        for (int ct = 0; ct < 8; ++ct) {
            f16x8 b = *(const f16x8*)&Wp[(size_t)((kb * 8 + ct) * 64 + lane) * 8];
            acc[0][ct] = __builtin_amdgcn_mfma_f32_16x16x32_f16(a0, b, acc[0][ct], 0, 0, 0);
            acc[1][ct] = __builtin_amdgcn_mfma_f32_16x16x32_f16(a1, b, acc[1][ct], 0, 0, 0);
        }
    }

    int c15 = lane & 15;
    #pragma unroll
    for (int s = 0; s < 2; ++s) {
        int rbase = row0 + s * 16 + kg * 4;
        float dv[4];
        #pragma unroll
        for (int r = 0; r < 4; ++r) {
            int rr = rbase + r; if (rr > NN - 1) rr = NN - 1;
            dv[r] = dis[rr];
        }
        #pragma unroll
        for (int ct = 0; ct < 8; ++ct) {
            int col = ct * 16 + c15;
            float bb = bias[col];
            #pragma unroll
            for (int r = 0; r < 4; ++r) {
                int rr = rbase + r;
                if (rr < NN) {
                    float v = acc[s][ct][r] + bb;
                    if (mode == 0) v = fmaxf(v, 0.f) * dv[r];
                    out[(size_t)rr * HID + col] = (_Float16)v;
                }
            }
        }
    }
}

// mean-pool per graph from fp16 h3; one wave per graph
__global__ __launch_bounds__(256) void k_pool16(const __half2* __restrict__ H, const int* __restrict__ gstart,
                                                float* __restrict__ pooled) {
    int wid = threadIdx.x >> 6;
    int lane = threadIdx.x & 63;
    int g = blockIdx.x * 4 + wid;
    if (g >= NG) return;
    int beg = gstart[g], end = gstart[g + 1];
    float ax = 0.f, ay = 0.f;
    for (int n = beg; n < end; ++n) {
        float2 f = __half22float2(H[n * 64 + lane]);
        ax += f.x; ay += f.y;
    }
    float inv = 1.f / fmaxf((float)(end - beg), 1.f);
    pooled[g * HID + lane * 2]     = ax * inv;
    pooled[g * HID + lane * 2 + 1] = ay * inv;
}

__global__ __launch_bounds__(64) void k_linear(const float* __restrict__ P, const float* __restrict__ Wl,
                                               const float* __restrict__ bl, float* __restrict__ out) {
    int g = blockIdx.x;
    int t = threadIdx.x;
    __shared__ float ps[HID];
    for (int k = t; k < HID; k += 64) ps[k] = P[g * HID + k];
    __syncthreads();
    if (t < NC) {
        float a = bl[t];
        #pragma unroll 4
        for (int k = 0; k < HID; ++k) a += ps[k] * Wl[k * NC + t];
        out[g * NC + t] = a;
    }
}

// ---------- launch ----------

extern "C" void kernel_launch(void* const* d_in, const int* in_sizes, int n_in,
                              void* d_out, int out_size, void* d_ws, size_t ws_size,
                              hipStream_t stream) {
    const float* x   = (const float*)d_in[0];
    const int* ei    = (const int*)d_in[1];
    const int* batch = (const int*)d_in[2];
    const float* W1 = (const float*)d_in[3];
    const float* b1 = (const float*)d_in[4];
    const float* W2 = (const float*)d_in[5];
    const float* b2 = (const float*)d_in[6];
    const float* W3 = (const float*)d_in[7];
    const float* b3 = (const float*)d_in[8];
    const float* Wl = (const float*)d_in[9];
    const float* bl = (const float*)d_in[10];
    float* out = (float*)d_out;

    char* ws = (char*)d_ws;
    size_t off = 0;
    auto alloc = [&](size_t bytes) -> void* {
        void* p = ws + off;
        off += (bytes + 255) & ~(size_t)255;
        return p;
    };
    int*          deg    = (int*)alloc((size_t)NN * 4);
    float*        dis    = (float*)alloc((size_t)NN * 4);
    int*          rp     = (int*)alloc((size_t)(NN + 1) * 4);
    int*          csr    = (int*)alloc((size_t)NE * 4);
    unsigned int* p1     = (unsigned int*)alloc((size_t)NE * 4);
    int*          gcur   = (int*)alloc(NBK * 4);
    int*          bsum   = (int*)alloc(512 * 4);
    int*          gstart = (int*)alloc((size_t)(NG + 1) * 4);
    float*        xsc    = (float*)alloc((size_t)NN * FIN * 4);
    float*        xa     = (float*)alloc((size_t)NN * FIN * 4);
    _Float16*     Wp2    = (_Float16*)alloc((size_t)HID * HID * 2);
    _Float16*     Wp3    = (_Float16*)alloc((size_t)HID * HID * 2);
    __half2*      Ht     = (__half2*)alloc((size_t)NN * HID * 2);
    __half2*      tb16   = (__half2*)alloc((size_t)NN * HID * 2);
    float*        pooled = (float*)alloc((size_t)NG * HID * 4);
    (void)ws_size; (void)in_sizes; (void)n_in; (void)out_size;

    hipMemsetAsync(deg, 0, (size_t)NN * 4, stream);
    hipMemsetAsync(gcur, 0, NBK * 4, stream);

    int eb  = (NE + 255) / 256;
    int nbv = (NN + 255) / 256;

    k_degree<<<eb, 256, 0, stream>>>(ei, deg);
    k_dis<<<nbv, 256, 0, stream>>>(deg, dis);
    k_scan1<<<nbv, 256, 0, stream>>>(deg, rp, bsum);
    k_scan2<<<1, 512, 0, stream>>>(bsum, nbv);
    k_scan3<<<nbv, 256, 0, stream>>>(rp, bsum);
    k_p1scatter<<<(NE + 4095) / 4096, 1024, 0, stream>>>(ei, rp, gcur, p1);
    k_p2fill<<<NBK, 1024, 0, stream>>>(p1, rp, csr);
    k_gstart<<<(NG + 256) / 256, 256, 0, stream>>>(batch, gstart);
    k_prescale<<<(NN * FIN + 255) / 256, 256, 0, stream>>>(x, dis, xsc);
    k_packW<<<8, 256, 0, stream>>>(W2, Wp2);
    k_packW<<<8, 256, 0, stream>>>(W3, Wp3);

    // layer 1
    k_agg11<<<(NN + 15) / 16, 256, 0, stream>>>(xsc, rp, csr, dis, xa);
    k_gemm11<<<(NN + 15) / 16, 256, 0, stream>>>(xa, W1, b1, dis, (__half*)Ht);

    // layer 2
    k_agg16<<<(NN + 3) / 4, 256, 0, stream>>>(Ht, rp, csr, dis, tb16);
    k_gemm128m<<<(NN + 127) / 128, 256, 0, stream>>>((const _Float16*)tb16, Wp2, b2, dis, (_Float16*)Ht, 0);

    // layer 3
    k_agg16<<<(NN + 3) / 4, 256, 0, stream>>>(Ht, rp, csr, dis, tb16);
    k_gemm128m<<<(NN + 127) / 128, 256, 0, stream>>>((const _Float16*)tb16, Wp3, b3, dis, (_Float16*)Ht, 1);

    k_pool16<<<(NG + 3) / 4, 256, 0, stream>>>(Ht, gstart, pooled);
    k_linear<<<NG, 64, 0, stream>>>(pooled, Wl, bl, out);
}

// Round 5
// 336.163 us; speedup vs baseline: 2.6131x; 1.2664x over previous
//
#include <hip/hip_runtime.h>
#include <hip/hip_bf16.h>
#include <hip/hip_fp16.h>

#define NN 100000
#define NE 1600000
#define NG 5000
#define FIN 11
#define HID 128
#define NC 19

#define NBK 98           // ceil(NN / 1024) buckets for CSR build
#define BKSH 10          // bucket = dst >> 10
#define BKMASK 1023
#define BCAP 20480       // fixed bucket capacity (mean 16384, +32 sigma)

typedef _Float16 f16x8 __attribute__((ext_vector_type(8)));
typedef _Float16 f16x4 __attribute__((ext_vector_type(4)));
typedef float f32x4 __attribute__((ext_vector_type(4)));

// ---------- CSR build (3 kernels) ----------

// Pass 1: bin edges by dst>>10 into fixed-capacity bucket regions, block-contiguous runs.
// pack = src (17b) | dst_low10 << 17
__global__ __launch_bounds__(1024) void k_p1scatter(const int* __restrict__ ei,
                                                    int* __restrict__ gcur, unsigned int* __restrict__ p1) {
    __shared__ int hist[NBK];
    __shared__ int base[NBK];
    __shared__ int lrank[NBK];
    int t = threadIdx.x;
    if (t < NBK) { hist[t] = 0; lrank[t] = 0; }
    __syncthreads();

    int e0 = blockIdx.x * 4096 + t * 4;
    int sr[4], dr[4], bk[4];
    if (e0 + 3 < NE) {
        int4 s4 = *(const int4*)(ei + e0);
        int4 d4 = *(const int4*)(ei + NE + e0);
        sr[0] = s4.x; sr[1] = s4.y; sr[2] = s4.z; sr[3] = s4.w;
        dr[0] = d4.x; dr[1] = d4.y; dr[2] = d4.z; dr[3] = d4.w;
        #pragma unroll
        for (int k = 0; k < 4; ++k) { bk[k] = dr[k] >> BKSH; atomicAdd(&hist[bk[k]], 1); }
    } else {
        #pragma unroll
        for (int k = 0; k < 4; ++k) {
            int e = e0 + k;
            if (e < NE) { sr[k] = ei[e]; dr[k] = ei[NE + e]; bk[k] = dr[k] >> BKSH; atomicAdd(&hist[bk[k]], 1); }
            else bk[k] = -1;
        }
    }
    __syncthreads();
    if (t < NBK && hist[t] > 0)
        base[t] = t * BCAP + atomicAdd(&gcur[t], hist[t]);
    __syncthreads();
    #pragma unroll
    for (int k = 0; k < 4; ++k) {
        if (bk[k] >= 0) {
            int slot = atomicAdd(&lrank[bk[k]], 1);
            p1[base[bk[k]] + slot] = (unsigned int)sr[k] | ((unsigned int)(dr[k] & BKMASK) << 17);
        }
    }
}

// tiny: exclusive scan of 98 bucket counts -> global csr bases; rp[NN]=NE
__global__ __launch_bounds__(64) void k_bucketbase(const int* __restrict__ gcur, int* __restrict__ bbase,
                                                   int* __restrict__ rp) {
    if (threadIdx.x == 0) {
        int acc = 0;
        for (int i = 0; i < NBK; ++i) {
            bbase[i] = acc;
            int c = gcur[i]; if (c > BCAP) c = BCAP;
            acc += c;
        }
        rp[NN] = acc;
    }
}

// Pass 2: per bucket: per-node degree count (LDS), block scan -> rp + dis, then exact placement.
__global__ __launch_bounds__(1024) void k_p2fill(const unsigned int* __restrict__ p1,
                                                 const int* __restrict__ gcur,
                                                 const int* __restrict__ bbase,
                                                 int* __restrict__ rp, int* __restrict__ csr,
                                                 float* __restrict__ dis) {
    __shared__ int cnt[1024];
    __shared__ int pf[1024];
    __shared__ int cur[1024];
    __shared__ int wsum[16];
    int bkt = blockIdx.x;
    int t = threadIdx.x;
    int v0 = bkt << BKSH;
    int nb = NN - v0; if (nb > 1024) nb = 1024;
    cnt[t] = 0; cur[t] = 0;
    __syncthreads();
    int count = gcur[bkt]; if (count > BCAP) count = BCAP;
    const unsigned int* reg = p1 + (size_t)bkt * BCAP;
    for (int i = t; i < count; i += 1024)
        atomicAdd(&cnt[reg[i] >> 17], 1);
    __syncthreads();
    int c = cnt[t];
    // block exclusive scan over 1024 counters
    int lane = t & 63, w = t >> 6;
    int val = c;
    #pragma unroll
    for (int off = 1; off < 64; off <<= 1) {
        int n = __shfl_up(val, off, 64);
        if (lane >= off) val += n;
    }
    if (lane == 63) wsum[w] = val;
    __syncthreads();
    if (w == 0) {
        int s = (lane < 16) ? wsum[lane] : 0;
        #pragma unroll
        for (int off = 1; off < 16; off <<= 1) {
            int n = __shfl_up(s, off, 64);
            if (lane >= off) s += n;
        }
        if (lane < 16) wsum[lane] = s;
    }
    __syncthreads();
    int wbase = (w == 0) ? 0 : wsum[w - 1];
    int excl = wbase + val - c;
    pf[t] = excl;
    int base = bbase[bkt];
    if (t < nb) {
        rp[v0 + t] = base + excl;
        dis[v0 + t] = rsqrtf((float)c + 1.0f);
    }
    __syncthreads();
    for (int i = t; i < count; i += 1024) {
        unsigned int u = reg[i];
        int dl = u >> 17;
        int off2 = atomicAdd(&cur[dl], 1);
        csr[base + pf[dl] + off2] = (int)(u & 0x1FFFFu);
    }
}

__global__ __launch_bounds__(256) void k_gstart(const int* __restrict__ batch, int* __restrict__ gstart) {
    int g = blockIdx.x * 256 + threadIdx.x;
    if (g > NG) return;
    int lo = 0, hi = NN;
    while (lo < hi) {
        int mid = (lo + hi) >> 1;
        if (batch[mid] < g) lo = mid + 1; else hi = mid;
    }
    gstart[g] = lo;
}

// xsc[v] = dis[v] * x[v]   (width 11)
__global__ __launch_bounds__(256) void k_prescale(const float* __restrict__ x, const float* __restrict__ dis,
                                                  float* __restrict__ xsc) {
    int i = blockIdx.x * 256 + threadIdx.x;
    if (i < NN * FIN) xsc[i] = x[i] * dis[i / FIN];
}

// pack W(128x128 fp32, k-major) into fp16 MFMA B-fragment order
__global__ __launch_bounds__(256) void k_packW(const float* __restrict__ W, _Float16* __restrict__ Wp) {
    int t = blockIdx.x * 256 + threadIdx.x;
    if (t >= 2048) return;
    int lane = t & 63;
    int tile = t >> 6;
    int kb = tile >> 3, ct = tile & 7;
    int kbase = kb * 32 + (lane >> 4) * 8;
    int col = ct * 16 + (lane & 15);
    f16x8 v;
    #pragma unroll
    for (int e = 0; e < 8; ++e) v[e] = (_Float16)W[(kbase + e) * HID + col];
    *(f16x8*)&Wp[(size_t)t * 8] = v;
}

// ---------- aggregation ----------

// xa[v] = dis[v] * ( sum_{s in N(v)} xsc[s] + xsc[v] )   (width 11; 16 lanes per node)
__global__ __launch_bounds__(256) void k_agg11(const float* __restrict__ xsc, const int* __restrict__ rp,
                                               const int* __restrict__ csr, const float* __restrict__ dis,
                                               float* __restrict__ xa) {
    int t = threadIdx.x;
    int q = t >> 4;
    int c = t & 15;
    int v = blockIdx.x * 16 + q;
    if (v >= NN) return;
    bool act = c < FIN;
    float acc = 0.f;
    int beg = rp[v], end = rp[v + 1];
    for (int e = beg; e < end; ++e) {
        int s = csr[e];
        if (act) acc += xsc[s * FIN + c];
    }
    if (act) {
        acc += xsc[v * FIN + c];
        xa[v * FIN + c] = acc * dis[v];
    }
}

// out16[v] = fp16( dis[v] * ( sum_{s in N(v)} Ht[s] + Ht[v] ) )
// One wave per node; lanes 0-31 = edge A, lanes 32-63 = edge B; 8 B per lane.
__global__ __launch_bounds__(256) void k_agg16(const _Float16* __restrict__ Ht, const int* __restrict__ rp,
                                               const int* __restrict__ csr, const float* __restrict__ dis,
                                               _Float16* __restrict__ out16) {
    int wid = threadIdx.x >> 6;
    int lane = threadIdx.x & 63;
    int v = blockIdx.x * 4 + wid;
    if (v >= NN) return;
    int hf = lane >> 5;         // which edge of the pair
    int l5 = lane & 31;         // 8-byte chunk (cols 4*l5 .. 4*l5+3)
    const _Float16* bp = Ht + (size_t)l5 * 4;
    int beg = rp[v], end = rp[v + 1];
    float a0 = 0, a1 = 0, a2 = 0, a3 = 0;
    float b0 = 0, b1 = 0, b2 = 0, b3 = 0;
    int e = beg;
    for (; e + 8 <= end; e += 8) {
        int s0 = csr[e + 0 + hf];
        int s1 = csr[e + 2 + hf];
        int s2 = csr[e + 4 + hf];
        int s3 = csr[e + 6 + hf];
        f16x4 h0 = *(const f16x4*)(bp + (size_t)s0 * HID);
        f16x4 h1 = *(const f16x4*)(bp + (size_t)s1 * HID);
        f16x4 h2 = *(const f16x4*)(bp + (size_t)s2 * HID);
        f16x4 h3 = *(const f16x4*)(bp + (size_t)s3 * HID);
        a0 += (float)h0[0]; a1 += (float)h0[1]; a2 += (float)h0[2]; a3 += (float)h0[3];
        b0 += (float)h1[0]; b1 += (float)h1[1]; b2 += (float)h1[2]; b3 += (float)h1[3];
        a0 += (float)h2[0]; a1 += (float)h2[1]; a2 += (float)h2[2]; a3 += (float)h2[3];
        b0 += (float)h3[0]; b1 += (float)h3[1]; b2 += (float)h3[2]; b3 += (float)h3[3];
    }
    for (; e < end; e += 2) {
        bool hasB = (e + 1 < end);
        int idx = e + hf; if (idx >= end) idx = end - 1;
        int s = csr[idx];
        f16x4 h = *(const f16x4*)(bp + (size_t)s * HID);
        float m = (hf && !hasB) ? 0.f : 1.f;
        a0 += m * (float)h[0]; a1 += m * (float)h[1];
        a2 += m * (float)h[2]; a3 += m * (float)h[3];
    }
    float t0 = a0 + b0, t1 = a1 + b1, t2 = a2 + b2, t3 = a3 + b3;
    t0 += __shfl_xor(t0, 32);
    t1 += __shfl_xor(t1, 32);
    t2 += __shfl_xor(t2, 32);
    t3 += __shfl_xor(t3, 32);
    if (hf == 0) {
        f16x4 sh = *(const f16x4*)(bp + (size_t)v * HID);
        float dv = dis[v];
        f16x4 o;
        o[0] = (_Float16)((t0 + (float)sh[0]) * dv);
        o[1] = (_Float16)((t1 + (float)sh[1]) * dv);
        o[2] = (_Float16)((t2 + (float)sh[2]) * dv);
        o[3] = (_Float16)((t3 + (float)sh[3]) * dv);
        *(f16x4*)(out16 + (size_t)v * HID + l5 * 4) = o;
    }
}

// ---------- dense compute ----------

// h1 = relu(xa(N x 11) @ W1(11 x 128) + b1); write Ht = fp16(dis*h1)
__global__ __launch_bounds__(256) void k_gemm11(const float* __restrict__ X, const float* __restrict__ W,
                                                const float* __restrict__ bias, const float* __restrict__ dis,
                                                __half* __restrict__ out16) {
    __shared__ float Ws[FIN][HID];
    __shared__ float Xs[16][FIN + 1];
    int t = threadIdx.x;
    int row0 = blockIdx.x * 16;
    for (int idx = t; idx < FIN * HID; idx += 256) Ws[idx / HID][idx % HID] = W[idx];
    for (int idx = t; idx < 16 * FIN; idx += 256) {
        int lin = row0 * FIN + idx;
        Xs[idx / FIN][idx % FIN] = (lin < NN * FIN) ? X[lin] : 0.f;
    }
    __syncthreads();
    int c = t & (HID - 1);
    int rg = t >> 7;
    #pragma unroll
    for (int i = 0; i < 8; ++i) {
        int r = rg * 8 + i;
        int row = row0 + r;
        if (row < NN) {
            float a = bias[c];
            #pragma unroll
            for (int k = 0; k < FIN; ++k) a += Xs[r][k] * Ws[k][c];
            a = fmaxf(a, 0.f);
            out16[row * HID + c] = __float2half(a * dis[row]);
        }
    }
}

// MFMA GEMM: out(N x 128) = X16(N x 128) @ W(128 x 128) + bias
// mode 0: relu, out = fp16(dis * h); mode 1: out = fp16(h)
__global__ __launch_bounds__(256) void k_gemm128m(const _Float16* __restrict__ X,
                                                  const _Float16* __restrict__ Wp,
                                                  const float* __restrict__ bias,
                                                  const float* __restrict__ dis,
                                                  _Float16* __restrict__ out, int mode) {
    int wave = threadIdx.x >> 6, lane = threadIdx.x & 63;
    int row0 = blockIdx.x * 128 + wave * 32;
    int rA = lane & 15, kg = lane >> 4;

    f32x4 acc[2][8];
    #pragma unroll
    for (int s = 0; s < 2; ++s)
        #pragma unroll
        for (int c = 0; c < 8; ++c)
            acc[s][c] = {0.f, 0.f, 0.f, 0.f};

    int r0c = row0 + rA;      if (r0c > NN - 1) r0c = NN - 1;
    int r1c = row0 + 16 + rA; if (r1c > NN - 1) r1c = NN - 1;
    const _Float16* xp0 = X + (size_t)r0c * HID + kg * 8;
    const _Float16* xp1 = X + (size_t)r1c * HID + kg * 8;

    #pragma unroll
    for (int kb = 0; kb < 4; ++kb) {
        f16x8 a0 = *(const f16x8*)(xp0 + kb * 32);
        f16x8 a1 = *(const f16x8*)(xp1 + kb * 32);
        #pragma unroll
        for (int ct = 0; ct < 8; ++ct) {
            f16x8 b = *(const f16x8*)&Wp[(size_t)((kb * 8 + ct) * 64 + lane) * 8];
            acc[0][ct] = __builtin_amdgcn_mfma_f32_16x16x32_f16(a0, b, acc[0][ct], 0, 0, 0);
            acc[1][ct] = __builtin_amdgcn_mfma_f32_16x16x32_f16(a1, b, acc[1][ct], 0, 0, 0);
        }
    }

    int c15 = lane & 15;
    #pragma unroll
    for (int s = 0; s < 2; ++s) {
        int rbase = row0 + s * 16 + kg * 4;
        float dv[4];
        #pragma unroll
        for (int r = 0; r < 4; ++r) {
            int rr = rbase + r; if (rr > NN - 1) rr = NN - 1;
            dv[r] = dis[rr];
        }
        #pragma unroll
        for (int ct = 0; ct < 8; ++ct) {
            int col = ct * 16 + c15;
            float bb = bias[col];
            #pragma unroll
            for (int r = 0; r < 4; ++r) {
                int rr = rbase + r;
                if (rr < NN) {
                    float v = acc[s][ct][r] + bb;
                    if (mode == 0) v = fmaxf(v, 0.f) * dv[r];
                    out[(size_t)rr * HID + col] = (_Float16)v;
                }
            }
        }
    }
}

// mean-pool per graph from fp16 h3; one wave per graph
__global__ __launch_bounds__(256) void k_pool16(const __half2* __restrict__ H, const int* __restrict__ gstart,
                                                float* __restrict__ pooled) {
    int wid = threadIdx.x >> 6;
    int lane = threadIdx.x & 63;
    int g = blockIdx.x * 4 + wid;
    if (g >= NG) return;
    int beg = gstart[g], end = gstart[g + 1];
    float ax = 0.f, ay = 0.f;
    for (int n = beg; n < end; ++n) {
        float2 f = __half22float2(H[n * 64 + lane]);
        ax += f.x; ay += f.y;
    }
    float inv = 1.f / fmaxf((float)(end - beg), 1.f);
    pooled[g * HID + lane * 2]     = ax * inv;
    pooled[g * HID + lane * 2 + 1] = ay * inv;
}

__global__ __launch_bounds__(64) void k_linear(const float* __restrict__ P, const float* __restrict__ Wl,
                                               const float* __restrict__ bl, float* __restrict__ out) {
    int g = blockIdx.x;
    int t = threadIdx.x;
    __shared__ float ps[HID];
    for (int k = t; k < HID; k += 64) ps[k] = P[g * HID + k];
    __syncthreads();
    if (t < NC) {
        float a = bl[t];
        #pragma unroll 4
        for (int k = 0; k < HID; ++k) a += ps[k] * Wl[k * NC + t];
        out[g * NC + t] = a;
    }
}

// ---------- launch ----------

extern "C" void kernel_launch(void* const* d_in, const int* in_sizes, int n_in,
                              void* d_out, int out_size, void* d_ws, size_t ws_size,
                              hipStream_t stream) {
    const float* x   = (const float*)d_in[0];
    const int* ei    = (const int*)d_in[1];
    const int* batch = (const int*)d_in[2];
    const float* W1 = (const float*)d_in[3];
    const float* b1 = (const float*)d_in[4];
    const float* W2 = (const float*)d_in[5];
    const float* b2 = (const float*)d_in[6];
    const float* W3 = (const float*)d_in[7];
    const float* b3 = (const float*)d_in[8];
    const float* Wl = (const float*)d_in[9];
    const float* bl = (const float*)d_in[10];
    float* out = (float*)d_out;

    char* ws = (char*)d_ws;
    size_t off = 0;
    auto alloc = [&](size_t bytes) -> void* {
        void* p = ws + off;
        off += (bytes + 255) & ~(size_t)255;
        return p;
    };
    float*        dis    = (float*)alloc((size_t)NN * 4);
    int*          rp     = (int*)alloc((size_t)(NN + 1) * 4);
    int*          csr    = (int*)alloc((size_t)NE * 4);
    unsigned int* p1     = (unsigned int*)alloc((size_t)NBK * BCAP * 4);
    int*          gcur   = (int*)alloc(NBK * 4);
    int*          bbase  = (int*)alloc(NBK * 4);
    int*          gstart = (int*)alloc((size_t)(NG + 1) * 4);
    float*        xsc    = (float*)alloc((size_t)NN * FIN * 4);
    float*        xa     = (float*)alloc((size_t)NN * FIN * 4);
    _Float16*     Wp2    = (_Float16*)alloc((size_t)HID * HID * 2);
    _Float16*     Wp3    = (_Float16*)alloc((size_t)HID * HID * 2);
    _Float16*     Ht     = (_Float16*)alloc((size_t)NN * HID * 2);
    _Float16*     tb16   = (_Float16*)alloc((size_t)NN * HID * 2);
    float*        pooled = (float*)alloc((size_t)NG * HID * 4);
    (void)ws_size; (void)in_sizes; (void)n_in; (void)out_size;

    hipMemsetAsync(gcur, 0, NBK * 4, stream);

    // CSR build
    k_p1scatter<<<(NE + 4095) / 4096, 1024, 0, stream>>>(ei, gcur, p1);
    k_bucketbase<<<1, 64, 0, stream>>>(gcur, bbase, rp);
    k_p2fill<<<NBK, 1024, 0, stream>>>(p1, gcur, bbase, rp, csr, dis);
    k_gstart<<<(NG + 256) / 256, 256, 0, stream>>>(batch, gstart);
    k_prescale<<<(NN * FIN + 255) / 256, 256, 0, stream>>>(x, dis, xsc);
    k_packW<<<8, 256, 0, stream>>>(W2, Wp2);
    k_packW<<<8, 256, 0, stream>>>(W3, Wp3);

    // layer 1
    k_agg11<<<(NN + 15) / 16, 256, 0, stream>>>(xsc, rp, csr, dis, xa);
    k_gemm11<<<(NN + 15) / 16, 256, 0, stream>>>(xa, W1, b1, dis, (__half*)Ht);

    // layer 2
    k_agg16<<<(NN + 3) / 4, 256, 0, stream>>>(Ht, rp, csr, dis, tb16);
    k_gemm128m<<<(NN + 127) / 128, 256, 0, stream>>>(tb16, Wp2, b2, dis, Ht, 0);

    // layer 3
    k_agg16<<<(NN + 3) / 4, 256, 0, stream>>>(Ht, rp, csr, dis, tb16);
    k_gemm128m<<<(NN + 127) / 128, 256, 0, stream>>>(tb16, Wp3, b3, dis, Ht, 1);

    k_pool16<<<(NG + 3) / 4, 256, 0, stream>>>((const __half2*)Ht, gstart, pooled);
    k_linear<<<NG, 64, 0, stream>>>(pooled, Wl, bl, out);
}